// Round 2
// baseline (606.651 us; speedup 1.0000x reference)
//
#include <hip/hip_runtime.h>
#include <hip/hip_bf16.h>

// BasicBlock (DoReFa 2-bit): BN1+ReLU+actquant -> conv3x3(wq1) -> BN2+ReLU+actquant
// -> conv3x3(wq2) -> + residual.
// Key identity: quantized acts = ia/3 (ia in 0..3), quantized weights = iw/3
// (iw in {-3,-1,1,3}) => conv = (sum ia*iw)/9. We run the integer GEMM on the
// bf16 MFMA pipe (exact in fp32 accum) and scale by 1/9 in the epilogue.
// ALL quantization decisions (round/clip boundaries) are made in f64 to match
// the harness's f64 numpy reference exactly -- f32 tanh/BN caused boundary
// flips worth absmax=2.0 in round 1.

typedef __bf16 bf16x8 __attribute__((ext_vector_type(8)));
typedef float f32x4 __attribute__((ext_vector_type(4)));
typedef unsigned short u16x4 __attribute__((ext_vector_type(4)));

#define A_ELEMS (32*58*58*256)          // padded NHWC activations (58 = 56+2 pad)
#define A_BYTES ((size_t)A_ELEMS*2)
#define WQ_ELEMS (256*2304)             // [kout][(r*3+s)*256+c] bf16 ints
#define WQ_BYTES ((size_t)WQ_ELEMS*2)
#define WN_ELEMS (256*256*9)            // 589824 weights per tensor

__device__ __forceinline__ void gload16(const void* g, void* l) {
  // async global->LDS, 16B per lane; dest is wave-uniform base + lane*16
  __builtin_amdgcn_global_load_lds((const __attribute__((address_space(1))) void*)g,
                                   (__attribute__((address_space(3))) void*)l, 16, 0, 0);
}

__device__ __forceinline__ unsigned short f2bf(float f) {
  // exact for small integers (0..3, +-1, +-3): low mantissa bits are zero
  return (unsigned short)(__float_as_uint(f) >> 16);
}

// ---------------- setup kernels ----------------

__global__ void bn_setup(const float* __restrict__ g1, const float* __restrict__ b1,
                         const float* __restrict__ m1, const float* __restrict__ v1,
                         const float* __restrict__ g2, const float* __restrict__ b2,
                         const float* __restrict__ m2, const float* __restrict__ v2,
                         double* __restrict__ invadd) {
  int t = threadIdx.x;  // 256 threads, 1 block
  double i1 = (double)g1[t] / sqrt((double)v1[t] + 1e-5);
  invadd[t]       = i1;
  invadd[256 + t] = (double)b1[t] - (double)m1[t] * i1;
  double i2 = (double)g2[t] / sqrt((double)v2[t] + 1e-5);
  invadd[512 + t] = i2;
  invadd[768 + t] = (double)b2[t] - (double)m2[t] * i2;
}

// zero only the pad ring of both padded activation buffers (ws is re-poisoned
// to 0xAA before every timed call, so this must run every call).
__global__ void zero_pad(unsigned short* __restrict__ A1, unsigned short* __restrict__ A2) {
  int idx = blockIdx.x * 256 + threadIdx.x;   // 2 * 32*228*32 vec8 stores
  unsigned short* A = A1;
  if (idx >= 233472) { A = A2; idx -= 233472; }
  int n = idx / 7296, rr = idx % 7296;        // 7296 = 228*32
  int p = rr >> 5, v8 = rr & 31;
  int hp, wp;
  if (p < 58)       { hp = 0;       wp = p; }
  else if (p < 116) { hp = 57;      wp = p - 58; }
  else if (p < 172) { hp = p - 115; wp = 0; }    // hp 1..56
  else              { hp = p - 171; wp = 57; }   // hp 1..56
  f32x4 z = {0.f, 0.f, 0.f, 0.f};
  *(f32x4*)(A + ((n*58 + hp)*58 + wp)*256 + v8*8) = z;
}

__global__ void wmax_kernel(const float* __restrict__ w1, const float* __restrict__ w2,
                            unsigned long long* __restrict__ slots) {
  int b = blockIdx.x;                 // 1024 blocks: 512 per tensor
  const float* w = w1; unsigned long long* slot = slots;
  if (b >= 512) { w = w2; slot = slots + 1; b -= 512; }
  double mx = 0.0;
  for (int i = b*256 + threadIdx.x; i < WN_ELEMS; i += 512*256)
    mx = fmax(mx, fabs(tanh((double)w[i])));
  #pragma unroll
  for (int off = 32; off; off >>= 1)
    mx = fmax(mx, __shfl_down(mx, off));
  __shared__ double red[4];
  if ((threadIdx.x & 63) == 0) red[threadIdx.x >> 6] = mx;
  __syncthreads();
  if (threadIdx.x == 0) {
    mx = fmax(fmax(red[0], red[1]), fmax(red[2], red[3]));
    atomicMax(slot, (unsigned long long)__double_as_longlong(mx)); // >=0: bits monotone
  }
}

__global__ void wquant_kernel(const float* __restrict__ w1, const float* __restrict__ w2,
                              const unsigned long long* __restrict__ slots,
                              unsigned short* __restrict__ Wq1,
                              unsigned short* __restrict__ Wq2) {
  int idx = blockIdx.x * 256 + threadIdx.x;   // 4608*256 == 2*WN_ELEMS exactly
  const float* w = w1; unsigned short* Wq = Wq1; int slot = 0;
  if (idx >= WN_ELEMS) { idx -= WN_ELEMS; w = w2; Wq = Wq2; slot = 1; }
  double wmax = __longlong_as_double((long long)slots[slot]);
  int kout = idx / 2304, k = idx % 2304;
  int r = k / 768, s = (k >> 8) % 3, c = k & 255;
  double wt = tanh((double)w[(kout*256 + c)*9 + r*3 + s]);  // OIHW source
  double wn = wt / (2.0 * wmax) + 0.5;                      // in [0,1], f64
  double iw = 2.0 * rint(wn * 3.0) - 3.0;                   // {-3,-1,1,3}
  Wq[kout*2304 + k] = f2bf((float)iw);                      // [kout][rs*256+c]
}

// BN1 + ReLU + act_quant, NCHW f32 -> padded NHWC bf16 ints, via LDS transpose.
// Quantization decision in f64 (matches f64 numpy reference).
__global__ void q1_kernel(const float* __restrict__ x, const double* __restrict__ invadd,
                          unsigned short* __restrict__ A1) {
  int b = blockIdx.x;                         // 32*56*4 blocks
  int ct = b & 3, h = (b >> 2) % 56, n = b / 224;
  int c0 = ct << 6;
  __shared__ float lds[64*57];                // 64 c x 56 w, pad 57 (conflict-free)
  const float* xp = x + (n*256 + c0)*3136 + h*56;
  for (int e = threadIdx.x; e < 64*14; e += 256) {     // float4 reads over w
    int i = e / 14, w4 = (e % 14) * 4;
    f32x4 v = *(const f32x4*)(xp + i*3136 + w4);
    float* d = &lds[i*57 + w4];
    d[0] = v[0]; d[1] = v[1]; d[2] = v[2]; d[3] = v[3];
  }
  __syncthreads();
  unsigned short* Ap = A1 + ((n*58 + h + 1)*58 + 1)*256 + c0;
  for (int e = threadIdx.x; e < 56*16; e += 256) {     // 8B writes over c
    int w = e >> 4, i4 = (e & 15) * 4;
    u16x4 pk;
    #pragma unroll
    for (int j = 0; j < 4; ++j) {
      int c = c0 + i4 + j;
      double bn = (double)lds[(i4 + j)*57 + w] * invadd[c] + invadd[256 + c];
      double q = rint(fmin(fmax(bn, 0.0), 1.0) * 3.0);  // relu+clip+quant, RNE
      pk[j] = f2bf((float)q);
    }
    *(u16x4*)(Ap + w*256 + i4) = pk;
  }
}

// ---------------- implicit-GEMM conv, bf16 MFMA 16x16x32 ----------------
// GEMM: M=100352 spatial, N=256 kout, K=2304=(r,s)x256c. 128x128 tile, BK=64,
// 4 waves (2x2 of 64x64), m97-style 2-barrier loop with global_load_lds(16B).
// LDS rows are 128B -> XOR chunk-swizzle (pre-swizzled SOURCE, linear dest).
// EPI=0: fuse BN2+ReLU+quant (f64 decision), write padded-NHWC bf16.
// EPI=1: +residual, f32 NCHW out.
template<int EPI>
__global__ __launch_bounds__(256) void conv_mfma(
    const unsigned short* __restrict__ Aq,   // padded NHWC bf16 ints
    const unsigned short* __restrict__ Wq,   // [kout][2304] bf16 ints
    const double* __restrict__ invadd,
    const float* __restrict__ xres,
    unsigned short* __restrict__ A2out,
    float* __restrict__ fout) {
  __shared__ __align__(16) char lds[32768];
  char* ldsA = lds;              // [128 rows][128 B]
  char* ldsB = lds + 16384;      // [128 cols][128 B]

  int bid = blockIdx.x;
  bid = (bid & 7) * 196 + (bid >> 3);        // XCD-chunked swizzle, 1568%8==0
  int nt = bid >> 1, ct = bid & 1;
  int M0 = nt * 128, N0 = ct * 128;

  int tid = threadIdx.x, lane = tid & 63, wv = tid >> 6;
  int wm = (wv >> 1) * 64, wn = (wv & 1) * 64;

  // staging precompute: wave wv stages A rows / B cols [wv*32, wv*32+32)
  int rbase = wv*32 + (lane >> 3);
  int jlog8 = ((lane & 7) ^ (lane >> 3)) * 8;  // swizzled source chunk (elems)
  int apre[4], bpre[4];
  #pragma unroll
  for (int t = 0; t < 4; ++t) {
    int row = rbase + t*8;
    int m = M0 + row;
    int n = m / 3136, rem = m % 3136;
    int h = rem / 56, w = rem % 56;
    apre[t] = ((n*58 + h)*58 + w)*256 + jlog8;   // padded origin: +r rows,+s cols later
    bpre[t] = (N0 + row)*2304 + jlog8;
  }

  f32x4 acc[4][4];
  #pragma unroll
  for (int i = 0; i < 4; ++i)
    #pragma unroll
    for (int j = 0; j < 4; ++j)
      acc[i][j] = (f32x4){0.f, 0.f, 0.f, 0.f};

  int lrow = lane & 15, lk = lane >> 4;

  for (int ks = 0; ks < 36; ++ks) {            // 9 (r,s) x 4 c-chunks, no tails
    int rs = ks >> 2, cs = ks & 3;
    int r = rs / 3, s = rs - r*3;
    int aoff = (r*58 + s)*256 + cs*64;
    int boff = rs*256 + cs*64;
    #pragma unroll
    for (int t = 0; t < 4; ++t) {
      gload16(Aq + apre[t] + aoff, ldsA + wv*4096 + t*1024);
      gload16(Wq + bpre[t] + boff, ldsB + wv*4096 + t*1024);
    }
    __syncthreads();                           // vmcnt drain by compiler
    #pragma unroll
    for (int kk = 0; kk < 2; ++kk) {
      bf16x8 af[4], bfr[4];
      #pragma unroll
      for (int f = 0; f < 4; ++f) {
        int arow = wm + f*16 + lrow;
        af[f]  = *(const bf16x8*)(ldsA + arow*128 + (((kk*4 + lk) ^ (arow & 7)) * 16));
        int bcol = wn + f*16 + lrow;
        bfr[f] = *(const bf16x8*)(ldsB + bcol*128 + (((kk*4 + lk) ^ (bcol & 7)) * 16));
      }
      #pragma unroll
      for (int fm = 0; fm < 4; ++fm)
        #pragma unroll
        for (int fn = 0; fn < 4; ++fn)
          acc[fm][fn] = __builtin_amdgcn_mfma_f32_16x16x32_bf16(af[fm], bfr[fn], acc[fm][fn], 0, 0, 0);
    }
    __syncthreads();
  }

  // epilogue. C/D layout (verified m89/m91): col = lane&15, row = (lane>>4)*4 + reg
  int lcol = lane & 15, lr4 = (lane >> 4) * 4;
  if (EPI == 0) {
    #pragma unroll
    for (int fm = 0; fm < 4; ++fm) {
      #pragma unroll
      for (int rr = 0; rr < 4; ++rr) {
        int m = M0 + wm + fm*16 + lr4 + rr;
        int n = m / 3136, rem = m % 3136, h = rem / 56, w = rem % 56;
        unsigned short* dst = A2out + ((n*58 + h + 1)*58 + (w + 1))*256;
        #pragma unroll
        for (int fn = 0; fn < 4; ++fn) {
          int col = N0 + wn + fn*16 + lcol;
          double v = (double)acc[fm][fn][rr] * (1.0/9.0);   // exact-int * 1/9, f64
          double bn = v * invadd[512 + col] + invadd[768 + col];
          double q = rint(fmin(fmax(bn, 0.0), 1.0) * 3.0);
          dst[col] = f2bf((float)q);
        }
      }
    }
  } else {
    #pragma unroll
    for (int fm = 0; fm < 4; ++fm) {
      int m = M0 + wm + fm*16 + lr4;          // rows m..m+3 share (n,h), w%4==0
      int n = m / 3136, rem = m % 3136, h = rem / 56, w = rem % 56;
      int base = n*802816 + h*56 + w;         // 802816 = 256*3136
      #pragma unroll
      for (int fn = 0; fn < 4; ++fn) {
        int col = N0 + wn + fn*16 + lcol;
        int idx = base + col*3136;
        f32x4 res = *(const f32x4*)(xres + idx);
        f32x4 o;
        #pragma unroll
        for (int rr = 0; rr < 4; ++rr)
          o[rr] = fmaf(acc[fm][fn][rr], 1.0f/9.0f, res[rr]);
        *(f32x4*)(fout + idx) = o;
      }
    }
  }
}

extern "C" void kernel_launch(void* const* d_in, const int* in_sizes, int n_in,
                              void* d_out, int out_size, void* d_ws, size_t ws_size,
                              hipStream_t stream) {
  const float* x  = (const float*)d_in[0];
  const float* w1 = (const float*)d_in[1];
  const float* w2 = (const float*)d_in[2];
  const float* g1 = (const float*)d_in[3];
  const float* b1 = (const float*)d_in[4];
  const float* m1 = (const float*)d_in[5];
  const float* v1 = (const float*)d_in[6];
  const float* g2 = (const float*)d_in[7];
  const float* b2 = (const float*)d_in[8];
  const float* m2 = (const float*)d_in[9];
  const float* v2 = (const float*)d_in[10];
  float* out = (float*)d_out;

  // ws layout: A1 | A2 | Wq1 | Wq2 | invadd(8KB f64) | wmax slots (~112.7 MB)
  if (ws_size < 2*A_BYTES + 2*WQ_BYTES + 8192 + 64) return;
  char* ws = (char*)d_ws;
  unsigned short* A1  = (unsigned short*)ws;
  unsigned short* A2  = (unsigned short*)(ws + A_BYTES);
  unsigned short* Wq1 = (unsigned short*)(ws + 2*A_BYTES);
  unsigned short* Wq2 = (unsigned short*)(ws + 2*A_BYTES + WQ_BYTES);
  double* invadd      = (double*)(ws + 2*A_BYTES + 2*WQ_BYTES);
  unsigned long long* slots = (unsigned long long*)(ws + 2*A_BYTES + 2*WQ_BYTES + 8192);

  hipMemsetAsync(slots, 0, 16, stream);
  zero_pad<<<1824, 256, 0, stream>>>(A1, A2);
  bn_setup<<<1, 256, 0, stream>>>(g1, b1, m1, v1, g2, b2, m2, v2, invadd);
  wmax_kernel<<<1024, 256, 0, stream>>>(w1, w2, slots);
  wquant_kernel<<<4608, 256, 0, stream>>>(w1, w2, slots, Wq1, Wq2);
  q1_kernel<<<7168, 256, 0, stream>>>(x, invadd, A1);
  conv_mfma<0><<<1568, 256, 0, stream>>>(A1, Wq1, invadd, nullptr, A2, nullptr);
  conv_mfma<1><<<1568, 256, 0, stream>>>(A2, Wq2, invadd, x, nullptr, out);
}

// Round 7
// 453.357 us; speedup vs baseline: 1.3381x; 1.3381x over previous
//
#include <hip/hip_runtime.h>
#include <hip/hip_bf16.h>

// BasicBlock (DoReFa 2-bit): BN1+ReLU+actquant -> conv3x3(wq1) -> BN2+ReLU+actquant
// -> conv3x3(wq2) -> + residual.
// Quantized acts = ia/3 (ia in 0..3), quantized weights = iw/3 (iw in {-3,-1,1,3})
// => conv = (sum ia*iw)/9 : an INTEGER GEMM on the i8 MFMA pipe
// (mfma_i32_16x16x64_i8: 2x bf16 rate, half the staging bytes). All quantization
// decisions in f64 (matches numpy f64 reference; f32 boundary flips = absmax 2.0 in r1).
// Weight quant via precomputed atanh thresholds: boundaries tanh(w) = {-2M/3, 0, 2M/3}
// <=> w = {-t, 0, t}, t = atanh(2M/3), M = tanh(max|w|) -- no per-weight tanh.

typedef float f32x4 __attribute__((ext_vector_type(4)));
typedef int   i32x4 __attribute__((ext_vector_type(4)));
typedef unsigned char u8x16 __attribute__((ext_vector_type(16)));

#define A_BYTES ((size_t)(32*58*58*256))   // padded NHWC i8 activations (58 = 56+2)
#define WQ_BYTES ((size_t)(256*2304))      // [kout][(r*3+s)*256+c] i8
#define WN_ELEMS (256*256*9)               // 589824 weights per tensor

__device__ __forceinline__ void gload16(const void* g, void* l) {
  // async global->LDS, 16B per lane; dest is wave-uniform base + lane*16
  __builtin_amdgcn_global_load_lds((const __attribute__((address_space(1))) void*)g,
                                   (__attribute__((address_space(3))) void*)l, 16, 0, 0);
}

// ---------------- setup kernels ----------------

// f32 abs-max of raw weights (exact; |tanh| monotone+odd so tanh applied once later)
__global__ void wmax_kernel(const float* __restrict__ w1, const float* __restrict__ w2,
                            unsigned* __restrict__ slots) {
  int b = blockIdx.x;                 // 1152 blocks: 576 per tensor, exact cover
  const float* w = w1; unsigned* slot = slots;
  if (b >= 576) { w = w2; slot = slots + 1; b -= 576; }
  f32x4 v = *(const f32x4*)(w + (size_t)(b*256 + threadIdx.x)*4);
  float mx = fmaxf(fmaxf(fabsf(v[0]), fabsf(v[1])), fmaxf(fabsf(v[2]), fabsf(v[3])));
  #pragma unroll
  for (int off = 32; off; off >>= 1)
    mx = fmaxf(mx, __shfl_down(mx, off));
  __shared__ float red[4];
  if ((threadIdx.x & 63) == 0) red[threadIdx.x >> 6] = mx;
  __syncthreads();
  if (threadIdx.x == 0) {
    mx = fmaxf(fmaxf(red[0], red[1]), fmaxf(red[2], red[3]));
    atomicMax(slot, __float_as_uint(mx));   // >=0: float bits monotone
  }
}

// BN coefficients in f64 + weight-quant thresholds t = atanh(2M/3). Runs AFTER wmax.
__global__ void bn_setup(const float* __restrict__ g1, const float* __restrict__ b1,
                         const float* __restrict__ m1, const float* __restrict__ v1,
                         const float* __restrict__ g2, const float* __restrict__ b2,
                         const float* __restrict__ m2, const float* __restrict__ v2,
                         const unsigned* __restrict__ slots,
                         double* __restrict__ invadd) {
  int t = threadIdx.x;  // 256 threads, 1 block
  double i1 = (double)g1[t] / sqrt((double)v1[t] + 1e-5);
  invadd[t]       = i1;
  invadd[256 + t] = (double)b1[t] - (double)m1[t] * i1;
  double i2 = (double)g2[t] / sqrt((double)v2[t] + 1e-5);
  invadd[512 + t] = i2;
  invadd[768 + t] = (double)b2[t] - (double)m2[t] * i2;
  if (t < 2) {
    double M = tanh((double)__uint_as_float(slots[t]));   // tanh(max|w|)
    invadd[1024 + t] = atanh((2.0/3.0) * M);              // boundary in w-space
  }
}

// zero the pad ring of both padded i8 activation buffers (ws re-poisoned each call)
__global__ void zero_pad(char* __restrict__ A1, char* __restrict__ A2) {
  int idx = blockIdx.x * 256 + threadIdx.x;   // 2 * 32*228*16 chunks of 16B
  char* A = A1;
  if (idx >= 116736) { A = A2; idx -= 116736; }
  int n = idx / 3648, rr = idx % 3648;        // 3648 = 228*16
  int p = rr >> 4, v = rr & 15;
  int hp, wp;
  if (p < 58)       { hp = 0;       wp = p; }
  else if (p < 116) { hp = 57;      wp = p - 58; }
  else if (p < 172) { hp = p - 115; wp = 0; }    // hp 1..56
  else              { hp = p - 171; wp = 57; }   // hp 1..56
  i32x4 z = {0, 0, 0, 0};
  *(i32x4*)(A + (size_t)((n*58 + hp)*58 + wp)*256 + v*16) = z;
}

// weight quant by threshold compare: q3 = rint(3*(tanh(w)/(2M)+0.5)) via w vs {-t,0,t}
__global__ void wquant_kernel(const float* __restrict__ w1, const float* __restrict__ w2,
                              const double* __restrict__ invadd,
                              char* __restrict__ Wq1, char* __restrict__ Wq2) {
  int idx = blockIdx.x * 256 + threadIdx.x;   // 4608*256 == 2*WN_ELEMS exactly
  const float* w = w1; char* Wq = Wq1; int slot = 0;
  if (idx >= WN_ELEMS) { idx -= WN_ELEMS; w = w2; Wq = Wq2; slot = 1; }
  double thr = invadd[1024 + slot];
  int kout = idx / 2304, k = idx % 2304;
  int r = k / 768, s = (k >> 8) % 3, c = k & 255;
  double wd = (double)w[(kout*256 + c)*9 + r*3 + s];        // OIHW source
  // w=0 -> v=1.5 -> rint ties-to-even -> 2 -> iw=+1 (handled by >= 0 branch)
  int q3 = (wd >= 0.0) ? (wd >= thr ? 3 : 2) : (wd >= -thr ? 1 : 0);
  Wq[kout*2304 + k] = (char)(2*q3 - 3);                     // {-3,-1,1,3}
}

// BN1 + ReLU + act_quant, NCHW f32 -> padded NHWC i8, one block per (n,h).
// 512 threads, LDS [256 c][57] f32. Writes fully coalesced 256B c-runs.
__global__ void q1_kernel(const float* __restrict__ x, const double* __restrict__ invadd,
                          char* __restrict__ A1) {
  int b = blockIdx.x;                         // 32*56 blocks
  int h = b % 56, n = b / 56;
  __shared__ float lds[256*57];
  const float* xp = x + (size_t)n*802816 + h*56;    // 802816 = 256*3136
  #pragma unroll
  for (int p = 0; p < 7; ++p) {               // 256 rows x 14 f32x4 = 3584 = 7*512
    int e = p*512 + threadIdx.x;
    int i = e / 14, w4 = (e % 14) * 4;
    f32x4 v = *(const f32x4*)(xp + (size_t)i*3136 + w4);
    float* d = &lds[i*57 + w4];
    d[0] = v[0]; d[1] = v[1]; d[2] = v[2]; d[3] = v[3];
  }
  __syncthreads();
  char* Ap = A1 + (size_t)((n*58 + h + 1)*58 + 1)*256;
  #pragma unroll
  for (int p = 0; p < 2; ++p) {               // 56 w x 16 chunks = 896 < 2*512
    int e = p*512 + threadIdx.x;
    if (e >= 896) break;
    int w = e >> 4, c16 = (e & 15) * 16;
    u8x16 pk;
    #pragma unroll
    for (int j = 0; j < 16; ++j) {
      int c = c16 + j;
      double bn = (double)lds[c*57 + w] * invadd[c] + invadd[256 + c];
      pk[j] = (unsigned char)(int)rint(fmin(fmax(bn, 0.0), 1.0) * 3.0);
    }
    *(u8x16*)(Ap + (size_t)w*256 + c16) = pk;
  }
}

// ---------------- implicit-GEMM conv, i8 MFMA 16x16x64 ----------------
// GEMM: M=100352 spatial, N=256 kout, K=2304=(r,s)x256c. 128x128 tile, BK=128 i8,
// 18 K-steps, 4 waves (2x2 of 64x64), 2-barrier loop, global_load_lds(16B).
// LDS rows 128B -> XOR chunk swizzle (linear dest + inverse-swizzled SOURCE + swz read).
// EPI=0: BN2+ReLU+quant (f64), LDS-transposed coalesced i8 NHWC writes.
// EPI=1: +residual, f32 NCHW direct stores.
template<int EPI>
__global__ __launch_bounds__(256) void conv_mfma(
    const char* __restrict__ Aq, const char* __restrict__ Wq,
    const double* __restrict__ invadd, const float* __restrict__ xres,
    char* __restrict__ A2out, float* __restrict__ fout) {
  __shared__ __align__(16) char lds[32768];
  char* ldsA = lds;              // [128 rows][128 B] (one BK=128 i8 K-slab)
  char* ldsB = lds + 16384;      // [128 cols][128 B]

  int bid = blockIdx.x;
  bid = (bid & 7) * 196 + (bid >> 3);        // XCD-chunked swizzle, 1568%8==0
  int nt = bid >> 1, ct = bid & 1;
  int M0 = nt * 128, N0 = ct * 128;

  int tid = threadIdx.x, lane = tid & 63, wv = tid >> 6;
  int wm = (wv >> 1) * 64, wn = (wv & 1) * 64;

  // staging: wave wv stages rows [wv*32, wv*32+32); lane -> row wv*32+q*8+(lane>>3),
  // physical chunk lane&7; source chunk = (lane&7)^(row&7), row&7 == lane>>3
  int srcch = ((lane & 7) ^ (lane >> 3)) * 16;
  int apre[4], bpre[4];
  #pragma unroll
  for (int q = 0; q < 4; ++q) {
    int row = wv*32 + q*8 + (lane >> 3);
    int m = M0 + row;
    int n = m / 3136, rem = m % 3136;
    int h = rem / 56, w = rem % 56;
    apre[q] = ((n*58 + h)*58 + w)*256 + srcch;   // pad origin; +(r,s) offset per step
    bpre[q] = (N0 + row)*2304 + srcch;
  }

  i32x4 acc[4][4];
  #pragma unroll
  for (int i = 0; i < 4; ++i)
    #pragma unroll
    for (int j = 0; j < 4; ++j)
      acc[i][j] = (i32x4){0, 0, 0, 0};

  int lrow = lane & 15, lk = lane >> 4;

  for (int ks = 0; ks < 18; ++ks) {            // 9 (r,s) x 2 half-c-chunks
    int rs = ks >> 1, half = ks & 1;
    int r = rs / 3, s = rs - r*3;
    int aoff = (r*58 + s)*256 + half*128;
    int boff = rs*256 + half*128;
    #pragma unroll
    for (int q = 0; q < 4; ++q) {
      gload16(Aq + apre[q] + aoff, ldsA + wv*4096 + q*1024);
      gload16(Wq + bpre[q] + boff, ldsB + wv*4096 + q*1024);
    }
    __syncthreads();                           // vmcnt drain by compiler
    #pragma unroll
    for (int kk = 0; kk < 2; ++kk) {
      i32x4 av[4], bv[4];
      #pragma unroll
      for (int f = 0; f < 4; ++f) {
        int arow = wm + f*16 + lrow;
        av[f] = *(const i32x4*)(ldsA + arow*128 + (((kk*4 + lk) ^ (arow & 7)) * 16));
        int bcol = wn + f*16 + lrow;
        bv[f] = *(const i32x4*)(ldsB + bcol*128 + (((kk*4 + lk) ^ (bcol & 7)) * 16));
      }
      #pragma unroll
      for (int fm = 0; fm < 4; ++fm)
        #pragma unroll
        for (int fn = 0; fn < 4; ++fn)
          acc[fm][fn] = __builtin_amdgcn_mfma_i32_16x16x64_i8(av[fm], bv[fn], acc[fm][fn], 0, 0, 0);
    }
    __syncthreads();
  }

  // epilogue. C/D layout (m89/m91, dtype-independent): col=lane&15, row=(lane>>4)*4+reg
  int lcol = lane & 15, lr4 = (lane >> 4) * 4;
  if (EPI == 0) {
    // BN2+ReLU+quant in f64, stage block's 128x128 i8 tile in LDS (XOR-swizzled),
    // then coalesced 16B row stores.
    #pragma unroll
    for (int fm = 0; fm < 4; ++fm) {
      #pragma unroll
      for (int rr = 0; rr < 4; ++rr) {
        int row = wm + fm*16 + lr4 + rr;
        #pragma unroll
        for (int fn = 0; fn < 4; ++fn) {
          int col = wn + fn*16 + lcol;
          int cg = N0 + col;
          double v = (double)acc[fm][fn][rr] * (1.0/9.0);
          double bn = v * invadd[512 + cg] + invadd[768 + cg];
          int q = (int)rint(fmin(fmax(bn, 0.0), 1.0) * 3.0);
          lds[row*128 + (col ^ ((row & 7) << 4))] = (char)q;
        }
      }
    }
    __syncthreads();
    #pragma unroll
    for (int p = 0; p < 4; ++p) {              // 32 rows/pass: 8 rows x 8 chunks per wave
      int row = p*32 + (tid >> 3), ch = tid & 7;
      int m = M0 + row;
      int n = m / 3136, rem = m % 3136, h = rem / 56, w = rem % 56;
      u8x16 val = *(const u8x16*)(lds + row*128 + ((ch ^ (row & 7)) * 16));
      *(u8x16*)(A2out + (size_t)((n*58 + h + 1)*58 + (w + 1))*256 + N0 + ch*16) = val;
    }
  } else {
    #pragma unroll
    for (int fm = 0; fm < 4; ++fm) {
      int m = M0 + wm + fm*16 + lr4;          // rows m..m+3 share (n,h), w%4==0
      int n = m / 3136, rem = m % 3136, h = rem / 56, w = rem % 56;
      int base = n*802816 + h*56 + w;         // 802816 = 256*3136
      #pragma unroll
      for (int fn = 0; fn < 4; ++fn) {
        int col = N0 + wn + fn*16 + lcol;
        int idx = base + col*3136;
        f32x4 res = *(const f32x4*)(xres + idx);
        f32x4 o;
        #pragma unroll
        for (int rr = 0; rr < 4; ++rr)
          o[rr] = fmaf((float)acc[fm][fn][rr], 1.0f/9.0f, res[rr]);
        *(f32x4*)(fout + idx) = o;
      }
    }
  }
}

extern "C" void kernel_launch(void* const* d_in, const int* in_sizes, int n_in,
                              void* d_out, int out_size, void* d_ws, size_t ws_size,
                              hipStream_t stream) {
  const float* x  = (const float*)d_in[0];
  const float* w1 = (const float*)d_in[1];
  const float* w2 = (const float*)d_in[2];
  const float* g1 = (const float*)d_in[3];
  const float* b1 = (const float*)d_in[4];
  const float* m1 = (const float*)d_in[5];
  const float* v1 = (const float*)d_in[6];
  const float* g2 = (const float*)d_in[7];
  const float* b2 = (const float*)d_in[8];
  const float* m2 = (const float*)d_in[9];
  const float* v2 = (const float*)d_in[10];
  float* out = (float*)d_out;

  // ws layout: A1 | A2 | Wq1 | Wq2 | invadd(8.5KB f64) | wmax slots  (~56.4 MB)
  if (ws_size < 2*A_BYTES + 2*WQ_BYTES + 8320 + 64) return;
  char* ws = (char*)d_ws;
  char* A1  = ws;
  char* A2  = ws + A_BYTES;
  char* Wq1 = ws + 2*A_BYTES;
  char* Wq2 = ws + 2*A_BYTES + WQ_BYTES;
  double* invadd  = (double*)(ws + 2*A_BYTES + 2*WQ_BYTES);
  unsigned* slots = (unsigned*)(ws + 2*A_BYTES + 2*WQ_BYTES + 8320);

  hipMemsetAsync(slots, 0, 8, stream);
  zero_pad<<<912, 256, 0, stream>>>(A1, A2);
  wmax_kernel<<<1152, 256, 0, stream>>>(w1, w2, slots);
  bn_setup<<<1, 256, 0, stream>>>(g1, b1, m1, v1, g2, b2, m2, v2, slots, invadd);
  wquant_kernel<<<4608, 256, 0, stream>>>(w1, w2, invadd, Wq1, Wq2);
  q1_kernel<<<1792, 512, 0, stream>>>(x, invadd, A1);
  conv_mfma<0><<<1568, 256, 0, stream>>>(A1, Wq1, invadd, nullptr, A2, nullptr);
  conv_mfma<1><<<1568, 256, 0, stream>>>(A2, Wq2, invadd, x, nullptr, out);
}